// Round 3
// baseline (738.331 us; speedup 1.0000x reference)
//
#include <hip/hip_runtime.h>
#include <hip/hip_bf16.h>

// Problem constants
#define H_IN   128
#define W_IN   128
#define B_SZ   64
#define CONV_O 126            // (128-2)
#define K_DIM  15876          // 126*126
#define N_TRI  8256           // 128*129/2
#define N_OUT  128
#define BK     32
#define BN     64
#define NSTEPS 497            // ceil(15876/32)
#define K8     1988           // NSTEPS*4 groups of 8 k-elements (zero-padded)
#define KSPLIT 8

typedef short  short8  __attribute__((ext_vector_type(8)));
typedef float  floatx4 __attribute__((ext_vector_type(4)));

__device__ inline short f2bf(float f) {
    union { __hip_bfloat16 h; short s; } u;
    u.h = __float2bfloat16(f);
    return u.s;
}

// ---------------------------------------------------------------------------
// Kernel 1: fused conv1(3x3,1->4)+bias+relu -> conv2(1x1,4->1)+bias.
// Output pre-swizzled to MFMA A-fragment order hsw[k8][m][j], zero-padded.
// ---------------------------------------------------------------------------
__global__ __launch_bounds__(256) void conv_kernel(
    const float* __restrict__ x,    // [64][1][128][128]
    const float* __restrict__ w1,   // [4][1][3][3]
    const float* __restrict__ b1,   // [4]
    const float* __restrict__ w2,   // [1][4][1][1]
    const float* __restrict__ b2,   // [1]
    unsigned short* __restrict__ hsw) // [K8][64][8] bf16
{
    int t = blockIdx.x * 256 + threadIdx.x;      // < K8*64*8
    int j  = t & 7;
    int m  = (t >> 3) & 63;
    int k8 = t >> 9;
    int p  = k8 * 8 + j;
    float val = 0.f;
    if (p < K_DIM) {
        int oy = p / CONV_O;
        int ox = p - oy * CONV_O;
        const float* xb = x + m * (H_IN * W_IN) + oy * W_IN + ox;
        float xin[9];
#pragma unroll
        for (int dy = 0; dy < 3; ++dy)
#pragma unroll
            for (int dx = 0; dx < 3; ++dx)
                xin[dy * 3 + dx] = xb[dy * W_IN + dx];
        float acc = b2[0];
#pragma unroll
        for (int c = 0; c < 4; ++c) {
            float s = b1[c];
#pragma unroll
            for (int q = 0; q < 9; ++q) s = fmaf(w1[c * 9 + q], xin[q], s);
            s = fmaxf(s, 0.f);
            acc = fmaf(w2[c], s, acc);
        }
        val = acc;
    }
    hsw[t] = (unsigned short)f2bf(val);
}

// ---------------------------------------------------------------------------
// Kernel 1b: init v[b][n] = out_b[n]  (bias pre-added; GEMM atomically adds)
// ---------------------------------------------------------------------------
__global__ __launch_bounds__(256) void init_v_kernel(
    const float* __restrict__ out_b, float* __restrict__ v)
{
    int t = blockIdx.x * 256 + threadIdx.x;   // < 64*N_TRI (padded grid)
    if (t < B_SZ * N_TRI) {
        int n = t % N_TRI;
        v[t] = out_b[n];
    }
}

// ---------------------------------------------------------------------------
// Kernel 2: v += h @ out_w^T. Tile M=64 x N=64 x K=32, 4 waves (2x2), wave
// tile 32x32. Depth-1 software pipeline: B(next)/A(next) prefetched into
// registers during MFMA of current step; LDS double-buffered -> ONE barrier
// per k-step, no exposed HBM latency on the critical path.
// ---------------------------------------------------------------------------
__global__ __launch_bounds__(256, 4) void gemm_kernel(
    const unsigned short* __restrict__ hsw, // [K8][64][8] bf16
    const float* __restrict__ w,            // [N_TRI][K_DIM] fp32
    float* __restrict__ v)                  // [64][N_TRI] fp32 (bias-inited)
{
    __shared__ __align__(16) short Bs[2][64 * 40];  // [buf][64 n][32 k] stride 40

    const int n0    = blockIdx.x * BN;
    const int split = blockIdx.y;
    const int s0 = (NSTEPS * split) / KSPLIT;
    const int s1 = (NSTEPS * (split + 1)) / KSPLIT;

    const int t    = threadIdx.x;
    const int lane = t & 63;
    const int wv   = t >> 6;
    const int quad = lane >> 4;
    const int l16  = lane & 15;

    const int mh = (wv >> 1) * 32;   // wave m-origin
    const int nq = (wv & 1) * 32;    // wave n-origin

    // B staging: 4 threads/row, 8 consecutive k each (32B contiguous)
    const int brow = t >> 2;
    const int bk   = (t & 3) * 8;
    const float* wbase = w + (size_t)(n0 + brow) * K_DIM + bk;

    // A fragment addresses
    const int aoff0 = (mh + l16) * 8;
    const int aoff1 = (mh + 16 + l16) * 8;

    floatx4 acc00 = {0.f,0.f,0.f,0.f}, acc01 = {0.f,0.f,0.f,0.f};
    floatx4 acc10 = {0.f,0.f,0.f,0.f}, acc11 = {0.f,0.f,0.f,0.f};

    // ---- preload tile s0 into registers
    float bv[8];
    short8 a0, a1;
    {
        const int k0 = s0 * BK;
        const float* wp = wbase + k0;
        if (k0 + BK <= K_DIM) {
            float4 x0 = *(const float4*)wp;
            float4 x1 = *(const float4*)(wp + 4);
            bv[0]=x0.x; bv[1]=x0.y; bv[2]=x0.z; bv[3]=x0.w;
            bv[4]=x1.x; bv[5]=x1.y; bv[6]=x1.z; bv[7]=x1.w;
        } else {
#pragma unroll
            for (int q = 0; q < 8; ++q)
                bv[q] = (k0 + bk + q < K_DIM) ? wp[q] : 0.f;
        }
        const unsigned short* ap = hsw + (size_t)(s0 * 4 + quad) * 512;
        a0 = *(const short8*)(ap + aoff0);
        a1 = *(const short8*)(ap + aoff1);
    }

    for (int s = s0; s < s1; ++s) {
        // ---- convert current B (waits on its global load) and stage to LDS
        short8 bs;
#pragma unroll
        for (int q = 0; q < 8; ++q) bs[q] = f2bf(bv[q]);
        short* buf = Bs[s & 1];
        *(short8*)(buf + brow * 40 + bk) = bs;

        // ---- prefetch next tile's B and A into registers (no wait here)
        const int sn = (s + 1 < s1) ? s + 1 : s;   // clamp (redundant reload on last)
        {
            const int k0n = sn * BK;
            const float* wp = wbase + k0n;
            if (k0n + BK <= K_DIM) {
                float4 x0 = *(const float4*)wp;
                float4 x1 = *(const float4*)(wp + 4);
                bv[0]=x0.x; bv[1]=x0.y; bv[2]=x0.z; bv[3]=x0.w;
                bv[4]=x1.x; bv[5]=x1.y; bv[6]=x1.z; bv[7]=x1.w;
            } else {
#pragma unroll
                for (int q = 0; q < 8; ++q)
                    bv[q] = (k0n + bk + q < K_DIM) ? wp[q] : 0.f;
            }
        }
        const unsigned short* apn = hsw + (size_t)(sn * 4 + quad) * 512;
        short8 a0n = *(const short8*)(apn + aoff0);
        short8 a1n = *(const short8*)(apn + aoff1);

        __syncthreads();   // Bs[s&1] fully staged (safe vs s-2 reads: they
                           // completed before each wave's previous barrier)

        // ---- consume: LDS B fragments + register A fragments -> 4 MFMA
        short8 b0 = *(const short8*)(buf + (nq + l16) * 40 + quad * 8);
        short8 b1 = *(const short8*)(buf + (nq + 16 + l16) * 40 + quad * 8);
        acc00 = __builtin_amdgcn_mfma_f32_16x16x32_bf16(a0, b0, acc00, 0, 0, 0);
        acc01 = __builtin_amdgcn_mfma_f32_16x16x32_bf16(a0, b1, acc01, 0, 0, 0);
        acc10 = __builtin_amdgcn_mfma_f32_16x16x32_bf16(a1, b0, acc10, 0, 0, 0);
        acc11 = __builtin_amdgcn_mfma_f32_16x16x32_bf16(a1, b1, acc11, 0, 0, 0);

        a0 = a0n; a1 = a1n;
    }

    // ---- epilogue: atomic accumulate partial sums
    const int nc = n0 + nq + l16;
#pragma unroll
    for (int r = 0; r < 4; ++r) {
        int m = mh + quad * 4 + r;
        atomicAdd(&v[(size_t)m * N_TRI + nc],              acc00[r]);
        atomicAdd(&v[(size_t)m * N_TRI + nc + 16],         acc01[r]);
        atomicAdd(&v[(size_t)(m + 16) * N_TRI + nc],       acc10[r]);
        atomicAdd(&v[(size_t)(m + 16) * N_TRI + nc + 16],  acc11[r]);
    }
}

// ---------------------------------------------------------------------------
// Kernel 3: symmetric triu scatter (bias already in v)
// ---------------------------------------------------------------------------
__global__ __launch_bounds__(256) void scatter_kernel(
    const float* __restrict__ v,      // [64][N_TRI] (includes bias)
    float* __restrict__ y)            // [64][1][128][128]
{
    int t = blockIdx.x * 256 + threadIdx.x;  // < 64*16384
    int b  = t >> 14;
    int ij = t & 16383;
    int i = ij >> 7, j = ij & 127;
    int ii = min(i, j), jj = max(i, j);
    int tri = ii * N_OUT - ((ii * (ii - 1)) >> 1) + (jj - ii);
    y[t] = v[(size_t)b * N_TRI + tri];
}

// ---------------------------------------------------------------------------
extern "C" void kernel_launch(void* const* d_in, const int* in_sizes, int n_in,
                              void* d_out, int out_size, void* d_ws, size_t ws_size,
                              hipStream_t stream) {
    const float* x   = (const float*)d_in[0];
    const float* c1w = (const float*)d_in[1];
    const float* c1b = (const float*)d_in[2];
    const float* c2w = (const float*)d_in[3];
    const float* c2b = (const float*)d_in[4];
    const float* ow  = (const float*)d_in[5];
    const float* ob  = (const float*)d_in[6];
    float* y = (float*)d_out;

    // workspace layout: hsw bf16 [K8][64][8] | v fp32 [64][N_TRI]
    unsigned short* hsw = (unsigned short*)d_ws;
    float* v = (float*)((char*)d_ws + (size_t)K8 * 64 * 8 * 2);  // 2,035,712 B

    conv_kernel<<<(K8 * 64 * 8) / 256, 256, 0, stream>>>(x, c1w, c1b, c2w, c2b, hsw);
    init_v_kernel<<<(B_SZ * N_TRI + 255) / 256, 256, 0, stream>>>(ob, v);
    gemm_kernel<<<dim3(N_TRI / BN, KSPLIT), 256, 0, stream>>>(hsw, ow, v);
    scatter_kernel<<<(B_SZ * N_OUT * N_OUT) / 256, 256, 0, stream>>>(v, y);
}